// Round 10
// baseline (904.039 us; speedup 1.0000x reference)
//
#include <hip/hip_runtime.h>

#define B_TOTAL   8192
#define CR_LEN    168
#define PR_LEN    24
#define HID       40
#define PAIRS     8            // row-pairs per block
#define ROWS      16           // rows per block
#define NTHREADS  320          // 8 pairs x 40 units = 5 full waves
#define XC_LEN    ((CR_LEN + PR_LEN) * 3)   // 576
#define OUT_STRIDE (B_TOTAL * PR_LEN)       // 196608

__device__ __forceinline__ float fast_rcp(float x) { return __builtin_amdgcn_rcpf(x); }

__device__ __forceinline__ float sigmoid_f(float x) {
    return fast_rcp(1.0f + __expf(-x));
}

__device__ __forceinline__ float tanh_f(float x) {
    float ax = fabsf(x);
    float e  = __expf(-2.0f * ax);
    float r  = (1.0f - e) * fast_rcp(1.0f + e);
    return copysignf(r, x);
}

__device__ __forceinline__ unsigned rotl32(unsigned x, int d) {
    return (x << d) | (x >> (32 - d));
}

// JAX threefry2x32 (20 rounds) — HW-KAT-verified (round 2)
__device__ __forceinline__ void threefry2x32(unsigned k0, unsigned k1,
                                             unsigned c0, unsigned c1,
                                             unsigned& o0, unsigned& o1) {
    const unsigned k2 = 0x1BD11BDAu ^ k0 ^ k1;
    unsigned x0 = c0 + k0, x1 = c1 + k1;
#define TF_R(rr) { x0 += x1; x1 = rotl32(x1, (rr)); x1 ^= x0; }
    TF_R(13) TF_R(15) TF_R(26) TF_R(6)  x0 += k1; x1 += k2 + 1u;
    TF_R(17) TF_R(29) TF_R(16) TF_R(24) x0 += k2; x1 += k0 + 2u;
    TF_R(13) TF_R(15) TF_R(26) TF_R(6)  x0 += k0; x1 += k1 + 3u;
    TF_R(17) TF_R(29) TF_R(16) TF_R(24) x0 += k1; x1 += k2 + 4u;
    TF_R(13) TF_R(15) TF_R(26) TF_R(6)  x0 += k2; x1 += k0 + 5u;
#undef TF_R
    o0 = x0; o1 = x1;
}

// Giles single-precision erfinv (XLA ErfInv32 poly)
__device__ __forceinline__ float erfinv_f(float x) {
    float w = -__logf(fmaf(-x, x, 1.0f));
    float p;
    if (w < 5.0f) {
        w -= 2.5f;
        p = 2.81022636e-08f;
        p = fmaf(p, w, 3.43273939e-07f);
        p = fmaf(p, w, -3.5233877e-06f);
        p = fmaf(p, w, -4.39150654e-06f);
        p = fmaf(p, w, 0.00021858087f);
        p = fmaf(p, w, -0.00125372503f);
        p = fmaf(p, w, -0.00417768164f);
        p = fmaf(p, w, 0.246640727f);
        p = fmaf(p, w, 1.50140941f);
    } else {
        w = sqrtf(w) - 3.0f;
        p = -0.000200214257f;
        p = fmaf(p, w, 0.000100950558f);
        p = fmaf(p, w, 0.00134934322f);
        p = fmaf(p, w, -0.00367342844f);
        p = fmaf(p, w, 0.00573950773f);
        p = fmaf(p, w, -0.0076224613f);
        p = fmaf(p, w, 0.00943887047f);
        p = fmaf(p, w, 1.00167406f);
        p = fmaf(p, w, 2.83297682f);
    }
    return p * x;
}

// KAT tripwire (Random123 vectors)
__device__ __forceinline__ float kat_poison() {
    float poison = 0.0f;
    unsigned o0, o1;
    threefry2x32(0u, 0u, 0u, 0u, o0, o1);
    bool ok1 = (o0 == 0x6b200159u) && (o1 == 0x99ba4efeu);
    threefry2x32(0xFFFFFFFFu, 0xFFFFFFFFu, 0xFFFFFFFFu, 0xFFFFFFFFu, o0, o1);
    bool ok2 = (o0 == 0x1cb996fcu) && (o1 == 0xbb002be7u);
    if (!(ok1 && ok2)) poison += 4096.0f;
    threefry2x32(0x13198a2eu, 0x03707344u, 0x243f6a88u, 0x85a308d3u, o0, o1);
    bool ok3 = (o0 == 0xc4923a9cu) && (o1 == 0x483df7a0u);
    if (!ok3) poison += 8192.0f;
    return poison;
}

// 4 fma's: acc += dot(w4, h4)
#define DOT4(acc, w4, h4) \
    acc = fmaf((w4).x, (h4).x, acc); acc = fmaf((w4).y, (h4).y, acc); \
    acc = fmaf((w4).z, (h4).z, acc); acc = fmaf((w4).w, (h4).w, acc);

// one h-quad step: 8 DOT4s (4 gates x 2 rows) sharing the streamed quads
#define QSTEP(q) do {                                                          \
    float4 h4A = hpA[q]; float4 h4B = hpB[q];                                  \
    DOT4(a0, wA##q, h4A) DOT4(b0, wA##q, h4B)                                  \
    DOT4(a1, wB##q, h4A) DOT4(b1, wB##q, h4B)                                  \
    DOT4(a2, wC##q, h4A) DOT4(b2, wC##q, h4B)                                  \
    DOT4(a3, wD##q, h4A) DOT4(b3, wD##q, h4B)                                  \
} while (0)

// load 10 named float4 weight quads for one gate row (plain loads: the
// compiler streams them from L1 each step — R4-proven best behavior)
#define LOADW(P, base)                                                         \
    const float4 P##0 = pw[(base) + 0], P##1 = pw[(base) + 1],                 \
                 P##2 = pw[(base) + 2], P##3 = pw[(base) + 3],                 \
                 P##4 = pw[(base) + 4], P##5 = pw[(base) + 5],                 \
                 P##6 = pw[(base) + 6], P##7 = pw[(base) + 7],                 \
                 P##8 = pw[(base) + 8], P##9 = pw[(base) + 9];

// x-path coefficients for one gate (embedding collapsed); row-independent
#define XCOEF(g, fAv, fCv, f0v, f1v, f2v) {                                    \
    const int row_ = (g) * HID + j;                                            \
    const float* wr_ = W_ih + row_ * 23;                                       \
    float a_ = 0.0f, cc_ = b_ih[row_] + b_hh[row_];                            \
    _Pragma("unroll")                                                          \
    for (int e = 0; e < 20; e++) {                                             \
        float wv_ = wr_[e];                                                    \
        a_  = fmaf(wv_, W_emb[e], a_);                                         \
        cc_ = fmaf(wv_, b_emb[e], cc_);                                        \
    }                                                                          \
    fAv = a_; fCv = cc_; f0v = wr_[20]; f1v = wr_[21]; f2v = wr_[22];          \
}

// two-row LSTM step (rows r0, r1 of this thread's pair)
#define LSTM2_STEP(zn0, xa0, xb0, xv0, zn1, xa1, xb1, xv1) do {                \
    float a0 = fmaf(fA0, (zn0), fC0), a1 = fmaf(fA1, (zn0), fC1);              \
    float a2 = fmaf(fA2, (zn0), fC2), a3 = fmaf(fA3, (zn0), fC3);              \
    float b0 = fmaf(fA0, (zn1), fC0), b1 = fmaf(fA1, (zn1), fC1);              \
    float b2 = fmaf(fA2, (zn1), fC2), b3 = fmaf(fA3, (zn1), fC3);              \
    a0 = fmaf(fp00, (xa0), a0); a1 = fmaf(fp01, (xa0), a1);                    \
    a2 = fmaf(fp02, (xa0), a2); a3 = fmaf(fp03, (xa0), a3);                    \
    b0 = fmaf(fp00, (xa1), b0); b1 = fmaf(fp01, (xa1), b1);                    \
    b2 = fmaf(fp02, (xa1), b2); b3 = fmaf(fp03, (xa1), b3);                    \
    a0 = fmaf(fp10, (xb0), a0); a1 = fmaf(fp11, (xb0), a1);                    \
    a2 = fmaf(fp12, (xb0), a2); a3 = fmaf(fp13, (xb0), a3);                    \
    b0 = fmaf(fp10, (xb1), b0); b1 = fmaf(fp11, (xb1), b1);                    \
    b2 = fmaf(fp12, (xb1), b2); b3 = fmaf(fp13, (xb1), b3);                    \
    a0 = fmaf(fp20, (xv0), a0); a1 = fmaf(fp21, (xv0), a1);                    \
    a2 = fmaf(fp22, (xv0), a2); a3 = fmaf(fp23, (xv0), a3);                    \
    b0 = fmaf(fp20, (xv1), b0); b1 = fmaf(fp21, (xv1), b1);                    \
    b2 = fmaf(fp22, (xv1), b2); b3 = fmaf(fp23, (xv1), b3);                    \
    const float4* hpA = (const float4*)&h_s[cur][r0][0];                       \
    const float4* hpB = (const float4*)&h_s[cur][r1][0];                       \
    QSTEP(0); QSTEP(1); QSTEP(2); QSTEP(3); QSTEP(4);                          \
    QSTEP(5); QSTEP(6); QSTEP(7); QSTEP(8); QSTEP(9);                          \
    float gi0 = sigmoid_f(a0), gf0 = sigmoid_f(a1);                            \
    float gg0 = tanh_f(a2),    go0 = sigmoid_f(a3);                            \
    c0_st = fmaf(gf0, c0_st, gi0 * gg0);                                       \
    h_s[cur ^ 1][r0][j] = go0 * tanh_f(c0_st);                                 \
    float gi1 = sigmoid_f(b0), gf1 = sigmoid_f(b1);                            \
    float gg1 = tanh_f(b2),    go1 = sigmoid_f(b3);                            \
    c1_st = fmaf(gf1, c1_st, gi1 * gg1);                                       \
    h_s[cur ^ 1][r1][j] = go1 * tanh_f(c1_st);                                 \
} while (0)

// mu/sigma/y head for one row (runs on the pair's j==0 thread)
#define HEAD(rr, t) do {                                                       \
    const int bglob_ = b_base + (rr);                                          \
    float mu = bmu_s, sp = bsg_s;                                              \
    const float4* hp_ = (const float4*)&h_s[cur ^ 1][rr][0];                   \
    _Pragma("unroll")                                                          \
    for (int q = 0; q < 10; q++) {                                             \
        float4 h4 = hp_[q];                                                    \
        float4 wm = *(const float4*)&wmu_s[4 * q];                             \
        float4 ws = *(const float4*)&wsg_s[4 * q];                             \
        mu = fmaf(wm.x, h4.x, mu); mu = fmaf(wm.y, h4.y, mu);                  \
        mu = fmaf(wm.z, h4.z, mu); mu = fmaf(wm.w, h4.w, mu);                  \
        sp = fmaf(ws.x, h4.x, sp); sp = fmaf(ws.y, h4.y, sp);                  \
        sp = fmaf(ws.z, h4.z, sp); sp = fmaf(ws.w, h4.w, sp);                  \
    }                                                                          \
    float sigma = fmaxf(sp, 0.0f) + log1pf(__expf(-fabsf(sp)));               \
    float y = fmaf(sigma, eps_s[rr][t], mu);                                   \
    y_s[rr] = y;                                                               \
    const float vv = v_s[rr];                                                  \
    const int ob = bglob_ * PR_LEN + (t);                                      \
    float poison = (bglob_ == 0 && (t) == 0) ? kat_poison() : 0.0f;            \
    out[ob]                  = y * vv + poison;                                \
    out[OUT_STRIDE + ob]     = mu * vv;                                        \
    out[2 * OUT_STRIDE + ob] = sigma * vv;                                     \
} while (0)

__launch_bounds__(NTHREADS, 1)
__global__ void deepar_kernel(const float* __restrict__ z1,
                              const float* __restrict__ xc,
                              const float* __restrict__ W_emb,
                              const float* __restrict__ b_emb,
                              const float* __restrict__ W_ih,
                              const float* __restrict__ b_ih,
                              const float* __restrict__ W_hh,
                              const float* __restrict__ b_hh,
                              const float* __restrict__ W_mu,
                              const float* __restrict__ b_mu,
                              const float* __restrict__ W_sig,
                              const float* __restrict__ b_sig,
                              float* __restrict__ out) {
    __shared__ __align__(16) float z1_s[ROWS][CR_LEN];
    __shared__ __align__(16) float xc_s[ROWS][XC_LEN];
    __shared__ __align__(16) float h_s[2][ROWS][HID];
    __shared__ float eps_s[ROWS][PR_LEN];
    __shared__ float y_s[ROWS];
    __shared__ float v_s[ROWS], iv_s[ROWS];
    __shared__ __align__(16) float wmu_s[HID];
    __shared__ __align__(16) float wsg_s[HID];
    __shared__ float bmu_s, bsg_s;

    const int tid = threadIdx.x;
    const int p   = tid / HID;          // pair 0..7
    const int j   = tid - p * HID;      // unit 0..39
    const int r0  = 2 * p, r1 = 2 * p + 1;
    const int b_base = blockIdx.x * ROWS;   // 512*16 == 8192 exact

    // ---- cooperative staging ----
    {
        const float4* s1 = (const float4*)(z1 + (size_t)b_base * CR_LEN);
        float4* d1 = (float4*)&z1_s[0][0];
        for (int idx = tid; idx < ROWS * (CR_LEN / 4); idx += NTHREADS) d1[idx] = s1[idx];
        const float4* s2 = (const float4*)(xc + (size_t)b_base * XC_LEN);
        float4* d2 = (float4*)&xc_s[0][0];
        for (int idx = tid; idx < ROWS * (XC_LEN / 4); idx += NTHREADS) d2[idx] = s2[idx];
    }
    if (tid < HID)                 wmu_s[tid] = W_mu[tid];
    else if (tid < 2 * HID)        wsg_s[tid - HID] = W_sig[tid - HID];
    else if (tid == 2 * HID)       bmu_s = b_mu[0];
    else if (tid == 2 * HID + 1)   bsg_s = b_sig[0];

    // ---- x-path coefficients (row-independent, shared by both rows) ----
    float fA0, fA1, fA2, fA3, fC0, fC1, fC2, fC3;
    float fp00, fp01, fp02, fp03, fp10, fp11, fp12, fp13, fp20, fp21, fp22, fp23;
    XCOEF(0, fA0, fC0, fp00, fp10, fp20)
    XCOEF(1, fA1, fC1, fp01, fp11, fp21)
    XCOEF(2, fA2, fC2, fp02, fp12, fp22)
    XCOEF(3, fA3, fC3, fp03, fp13, fp23)

    // ---- W_hh gate rows (streamed by compiler; used 8x per quad) ----
    const float4* pw = (const float4*)W_hh;
    LOADW(wA, (0 * HID + j) * 10)
    LOADW(wB, (1 * HID + j) * 10)
    LOADW(wC, (2 * HID + j) * 10)
    LOADW(wD, (3 * HID + j) * 10)

    __syncthreads();   // staging ready

    // ---- v per row (threads 0..15) ----
    if (tid < ROWS) {
        float s = 0.0f;
#pragma unroll
        for (int q = 0; q < CR_LEN / 4; q++) {
            float4 zz = *(const float4*)&z1_s[tid][4 * q];
            s += zz.x + zz.y + zz.z + zz.w;
        }
        float v = s * (1.0f / (float)CR_LEN) + 1.0f;
        v_s[tid]  = v;
        iv_s[tid] = 1.0f / v;
    }

    // ---- eps (384 values over 320 threads) ----
    for (int idx = tid; idx < ROWS * PR_LEN; idx += NTHREADS) {
        const int row_ = idx / PR_LEN;
        const int tt   = idx - row_ * PR_LEN;
        unsigned i = (unsigned)tt * B_TOTAL + (unsigned)(b_base + row_);
        unsigned o0, o1;
        threefry2x32(0u, 42u, 0u, i, o0, o1);
        unsigned bits = o0 ^ o1;
        float f = __uint_as_float((bits >> 9) | 0x3F800000u) - 1.0f;
        const float lo = -0.99999994f;
        float uu = fmaxf(lo, fmaf(f, 2.0f, lo));
        eps_s[row_][tt] = 1.41421356237f * erfinv_f(uu);
    }

    h_s[0][r0][j] = 0.0f;
    h_s[0][r1][j] = 0.0f;
    float c0_st = 0.0f, c1_st = 0.0f;
    __syncthreads();

    const float iv0 = iv_s[r0], iv1 = iv_s[r1];
    int cur = 0;

    // ---- conditioning: t = 0..166, ONE barrier per step for 2 rows ----
    for (int t = 0; t < CR_LEN - 1; t++) {
        const int xo = 3 * (t + 1);
        LSTM2_STEP(z1_s[r0][t] * iv0, xc_s[r0][xo], xc_s[r0][xo + 1], xc_s[r0][xo + 2],
                   z1_s[r1][t] * iv1, xc_s[r1][xo], xc_s[r1][xo + 1], xc_s[r1][xo + 2]);
        __syncthreads();
        cur ^= 1;
    }

    if (j == 0) { y_s[r0] = z1_s[r0][CR_LEN - 1]; y_s[r1] = z1_s[r1][CR_LEN - 1]; }
    __syncthreads();

    // ---- prediction: t = 0..23 (2 barriers per step: h, then y) ----
    for (int t = 0; t < PR_LEN; t++) {
        const int xo = 3 * (CR_LEN + t);
        LSTM2_STEP(y_s[r0] * iv0, xc_s[r0][xo], xc_s[r0][xo + 1], xc_s[r0][xo + 2],
                   y_s[r1] * iv1, xc_s[r1][xo], xc_s[r1][xo + 1], xc_s[r1][xo + 2]);
        __syncthreads();
        if (j == 0) { HEAD(r0, t); HEAD(r1, t); }
        __syncthreads();
        cur ^= 1;
    }
}

extern "C" void kernel_launch(void* const* d_in, const int* in_sizes, int n_in,
                              void* d_out, int out_size, void* d_ws, size_t ws_size,
                              hipStream_t stream) {
    const float* z1    = (const float*)d_in[0];
    const float* xc    = (const float*)d_in[1];
    const float* W_emb = (const float*)d_in[2];
    const float* b_emb = (const float*)d_in[3];
    const float* W_ih  = (const float*)d_in[4];
    const float* b_ih  = (const float*)d_in[5];
    const float* W_hh  = (const float*)d_in[6];
    const float* b_hh  = (const float*)d_in[7];
    const float* W_mu  = (const float*)d_in[8];
    const float* b_mu  = (const float*)d_in[9];
    const float* W_sig = (const float*)d_in[10];
    const float* b_sig = (const float*)d_in[11];
    float* out = (float*)d_out;

    dim3 grid(B_TOTAL / ROWS);   // 512 — exactly 2 blocks/CU, one pass
    dim3 block(NTHREADS);        // 320
    deepar_kernel<<<grid, block, 0, stream>>>(z1, xc, W_emb, b_emb, W_ih, b_ih,
                                              W_hh, b_hh, W_mu, b_mu, W_sig, b_sig,
                                              out);
}